// Round 5
// baseline (231.464 us; speedup 1.0000x reference)
//
#include <hip/hip_runtime.h>
#include <hip/hip_bf16.h>
#include <stdint.h>

#define BATCH 32
#define SRCN 1024
#define SEQL 128
#define CTXN 5
#define DMOD 512

typedef __attribute__((ext_vector_type(8))) short short8;
typedef __attribute__((ext_vector_type(4))) float floatx4;

typedef __attribute__((address_space(3))) void lds_t;
typedef __attribute__((address_space(1))) void glb_t;

__device__ __forceinline__ void gload_lds16(const void* g, void* l) {
    __builtin_amdgcn_global_load_lds((const glb_t*)g, (lds_t*)l, 16, 0, 0);
}

__device__ __forceinline__ ushort f2b(float f) {
    __hip_bfloat16 h = __float2bfloat16(f);
    return *reinterpret_cast<ushort*>(&h);
}

// Swizzled LDS slot for (tile-local row m, k-seg sg): slot = m*8 + (sg^(m&7)),
// slot = 8 ushorts (16B). Staging chunk cc (1KB = 8 rows x 64k): lane i stages
// row cc*8+(i>>3), k-seg (i&7)^(i>>3) -> 8 contiguous 128B runs, and the LDS
// dest is exactly chunkbase + lane*16 (wave-uniform base + lane*size).
#define LSLOT(m, sg) ((((m) << 3) | ((sg) ^ ((m) & 7))) << 3)

// Pw transpose tile stride: 69 floats/row; 8*69 % 32 = 8 -> spread banks.
#define PSTR 69

// ---------------------------------------------------------------------------
// Merged gather: blocks [0,4096) yce gather; [4096,4416) P_w transpose;
// [4416,6464) F gather -> xe + xet (128x x 64d tiles, swizzled LDS transpose).
// ---------------------------------------------------------------------------
__global__ __launch_bounds__(256) void k_gather(
    const int* __restrict__ yc, const float* __restrict__ G,
    ushort* __restrict__ yce,
    const float* __restrict__ Pw, ushort* __restrict__ Pwt,
    const int* __restrict__ x, const float* __restrict__ F,
    ushort* __restrict__ xe, ushort* __restrict__ xet)
{
    __shared__ __align__(16) char smem[17664];
    const int tid = threadIdx.x;
    const int bid = blockIdx.x;
    if (bid < 4096) {
        // ---- gather yce[b][s][c*512 + d] bf16 ----
        int* toks = (int*)smem;
        const int r = bid;                   // b*128+s
        const int b = r >> 7, s = r & 127;
        if (tid < CTXN) toks[tid] = yc[b * (SEQL * CTXN) + s * CTXN + tid];
        __syncthreads();
        for (int i = tid; i < 640; i += 256) {
            const int c = i >> 7;            // context slot 0..4
            const int tok = toks[c];
            const float4 v = *(const float4*)(G + (size_t)tok * DMOD + (i & 127) * 4);
            ushort4 o;
            o.x = f2b(v.x); o.y = f2b(v.y); o.z = f2b(v.z); o.w = f2b(v.w);
            *(ushort4*)(yce + (size_t)r * 2560 + i * 4) = o;
        }
    } else if (bid < 4416) {
        // ---- transpose P_w [2560][512] -> Pwt [512][2560] bf16 ----
        float* tf = (float*)smem;            // [64][PSTR]
        const int id = bid - 4096;           // 0..319
        const int k0 = (id % 40) * 64, n0 = (id / 40) * 64;
        #pragma unroll
        for (int it = 0; it < 4; ++it) {
            const int c = tid + it * 256;
            const int kr = c >> 4, c4 = c & 15;
            const float4 v = *(const float4*)(Pw + (size_t)(k0 + kr) * DMOD + n0 + c4 * 4);
            tf[kr * PSTR + c4 * 4 + 0] = v.x; tf[kr * PSTR + c4 * 4 + 1] = v.y;
            tf[kr * PSTR + c4 * 4 + 2] = v.z; tf[kr * PSTR + c4 * 4 + 3] = v.w;
        }
        __syncthreads();
        #pragma unroll
        for (int it = 0; it < 2; ++it) {
            const int c = tid + it * 256;
            const int n = c >> 3, seg = c & 7;
            ushort4 o0, o1;
            o0.x = f2b(tf[(seg * 8 + 0) * PSTR + n]); o0.y = f2b(tf[(seg * 8 + 1) * PSTR + n]);
            o0.z = f2b(tf[(seg * 8 + 2) * PSTR + n]); o0.w = f2b(tf[(seg * 8 + 3) * PSTR + n]);
            o1.x = f2b(tf[(seg * 8 + 4) * PSTR + n]); o1.y = f2b(tf[(seg * 8 + 5) * PSTR + n]);
            o1.z = f2b(tf[(seg * 8 + 6) * PSTR + n]); o1.w = f2b(tf[(seg * 8 + 7) * PSTR + n]);
            ushort* dst = Pwt + (size_t)(n0 + n) * 2560 + k0 + seg * 8;
            *(ushort4*)dst = o0; *(ushort4*)(dst + 4) = o1;
        }
    } else {
        // ---- gather F rows -> xe[b][x][d] AND xet[b][d][x] bf16 ----
        ushort* t = (ushort*)smem;           // [128*64]
        int* toks = (int*)(smem + 16384);    // 128 ints
        const int id = bid - 4416;           // 0..2047
        const int z = id >> 6;               // batch
        const int rem = id & 63;
        const int x0 = (rem & 7) * 128, d0 = (rem >> 3) * 64;
        if (tid < 128) toks[tid] = x[z * SRCN + x0 + tid];
        __syncthreads();
        #pragma unroll
        for (int it = 0; it < 8; ++it) {
            const int c = tid + it * 256;    // 2048 chunks: 128 rows x 16 float4
            const int row = c >> 4, seg = c & 15;
            const int tok = toks[row];
            const float4 v = *(const float4*)(F + (size_t)tok * DMOD + d0 + seg * 4);
            ushort4 o;
            o.x = f2b(v.x); o.y = f2b(v.y); o.z = f2b(v.z); o.w = f2b(v.w);
            const int sg2 = seg ^ ((row >> 3) & 15);
            *(ushort4*)&t[row * 64 + sg2 * 4] = o;
            *(ushort4*)(xe + (size_t)(z * SRCN + x0 + row) * DMOD + d0 + seg * 4) = o;
        }
        __syncthreads();
        #pragma unroll
        for (int it = 0; it < 4; ++it) {
            const int c = tid + it * 256;    // 1024 outs: 16 xs (fast) x 64 d
            const int xs = c & 15, d = c >> 4;
            const int sbase = ((d >> 2) ^ xs) * 4 + (d & 3);
            short8 o;
            #pragma unroll
            for (int r = 0; r < 8; ++r)
                o[r] = (short)t[(xs * 8 + r) * 64 + sbase];
            *(short8*)(xet + (size_t)(z * DMOD + d0 + d) * SRCN + x0 + xs * 8) = o;
        }
    }
}

// ---------------------------------------------------------------------------
// GEMM1 (split-K=2, 2-phase pipelined): part[ks] = yce[., ks*1280:] @ pwt^T.
// Tile 128m x 64n, BK=64 double-buffered: STAGE(next) issued BEFORE compute,
// so the barrier's vmcnt(0) drain overlaps the MFMA work. 512 blocks.
// ---------------------------------------------------------------------------
__global__ __launch_bounds__(256) void k_gemm_py(
    const ushort* __restrict__ yce, const ushort* __restrict__ pwt,
    float* __restrict__ part)
{
    __shared__ ushort As[2 * 8192];   // dbuf x (128 rows x 64 k)
    __shared__ ushort Bs[2 * 4096];   // dbuf x (64 rows x 64 k)
    const int f = blockIdx.x;         // 0..511
    const int ks  = f >> 8;
    const int idx = f & 255;
    const int mlo = idx & 7;
    const int n   = (idx >> 3) & 7;
    const int mhi = idx >> 6;
    const int m = mlo | (mhi << 3);   // 0..31
    const int tid = threadIdx.x;
    const int w = tid >> 6, lane = tid & 63;
    const int l15 = lane & 15, q = lane >> 4;
    const int wm = w >> 1, wn = w & 1;
    const int m0 = m * 128, n0 = n * 64, koff = ks * 1280;

    const int sr = lane >> 3;
    const int ssg = ((lane & 7) ^ sr) * 8;

    const ushort* Abase = yce + (size_t)(m0 + sr) * 2560 + koff + ssg;
    const ushort* Bbase = pwt + (size_t)(n0 + sr) * 2560 + koff + ssg;

    floatx4 acc[4][2];
    #pragma unroll
    for (int mi = 0; mi < 4; ++mi)
        #pragma unroll
        for (int ni = 0; ni < 2; ++ni)
            acc[mi][ni] = (floatx4){0.f, 0.f, 0.f, 0.f};

#define STAGE_PY(buf, kk) do { \
    _Pragma("unroll") \
    for (int i = 0; i < 4; ++i) { \
        const int cc = w * 4 + i; \
        gload_lds16(Abase + (size_t)(cc * 8) * 2560 + (kk), (void*)(As + (buf) * 8192 + cc * 512)); \
    } \
    _Pragma("unroll") \
    for (int i = 0; i < 2; ++i) { \
        const int cc = w * 2 + i; \
        gload_lds16(Bbase + (size_t)(cc * 8) * 2560 + (kk), (void*)(Bs + (buf) * 4096 + cc * 512)); \
    } } while (0)

    STAGE_PY(0, 0);
    __syncthreads();
    #pragma unroll
    for (int t = 0; t < 20; ++t) {
        const int cur = t & 1;
        if (t < 19) STAGE_PY(cur ^ 1, (t + 1) * 64);
        #pragma unroll
        for (int s2 = 0; s2 < 2; ++s2) {
            const int sg = s2 * 4 + q;
            short8 af[4], bf[2];
            #pragma unroll
            for (int mi = 0; mi < 4; ++mi)
                af[mi] = *(const short8*)(As + cur * 8192 + LSLOT(wm * 64 + mi * 16 + l15, sg));
            #pragma unroll
            for (int ni = 0; ni < 2; ++ni)
                bf[ni] = *(const short8*)(Bs + cur * 4096 + LSLOT(wn * 32 + ni * 16 + l15, sg));
            #pragma unroll
            for (int mi = 0; mi < 4; ++mi)
                #pragma unroll
                for (int ni = 0; ni < 2; ++ni)
                    acc[mi][ni] = __builtin_amdgcn_mfma_f32_16x16x32_bf16(
                        af[mi], bf[ni], acc[mi][ni], 0, 0, 0);
        }
        __syncthreads();
    }
#undef STAGE_PY

    float* dst = part + (size_t)ks * (4096LL * DMOD);
    #pragma unroll
    for (int ni = 0; ni < 2; ++ni) {
        const int col = n0 + wn * 32 + ni * 16 + l15;
        #pragma unroll
        for (int mi = 0; mi < 4; ++mi) {
            const int row0 = m0 + wm * 64 + mi * 16 + q * 4;
            #pragma unroll
            for (int r = 0; r < 4; ++r)
                dst[(size_t)(row0 + r) * DMOD + col] = acc[mi][ni][r];
        }
    }
}

// ---------------------------------------------------------------------------
// Reduce 2 split-K partials + bias -> py bf16 [4096][512]
// ---------------------------------------------------------------------------
__global__ __launch_bounds__(256) void k_red2(
    const float* __restrict__ part, const float* __restrict__ Pb,
    ushort* __restrict__ py)
{
    const long long SL = 4096LL * DMOD;
    const int i = blockIdx.x * 256 + threadIdx.x;   // vec4 id, 524288 total
    const float4 a = *(const float4*)(part + (size_t)i * 4);
    const float4 b = *(const float4*)(part + SL + (size_t)i * 4);
    const float4 bias = *(const float4*)(Pb + ((i * 4) & 511));
    ushort4 o;
    o.x = f2b(a.x + b.x + bias.x);
    o.y = f2b(a.y + b.y + bias.y);
    o.z = f2b(a.z + b.z + bias.z);
    o.w = f2b(a.w + b.w + bias.w);
    *(ushort4*)(py + (size_t)i * 4) = o;
}

// ---------------------------------------------------------------------------
// GEMM2 (2-phase pipelined): a[b][0:128][n0:n0+64] = py_b @ xe_b^T (K=512),
// mask fused, fp32 out. Tile 128m x 64n dbuf BK=64, 512 blocks.
// ---------------------------------------------------------------------------
__global__ __launch_bounds__(256) void k_gemm_sc(
    const ushort* __restrict__ py, const int* __restrict__ x,
    const ushort* __restrict__ xe, float* __restrict__ a_out)
{
    __shared__ ushort As[2 * 8192];   // dbuf x (128 rows x 64 k)
    __shared__ ushort Bs[2 * 4096];   // dbuf x (64 rows x 64 k)
    const int f = blockIdx.x;         // 0..511
    const int g = f >> 3;
    const int b = ((g & 3) << 3) | (f & 7);
    const int n = g >> 2;             // 0..15
    const int tid = threadIdx.x;
    const int w = tid >> 6, lane = tid & 63;
    const int l15 = lane & 15, q = lane >> 4;
    const int wm = w >> 1, wn = w & 1;
    const int n0 = n * 64;

    const int sr = lane >> 3;
    const int ssg = ((lane & 7) ^ sr) * 8;

    const ushort* Abase = py + (size_t)(b * SEQL + sr) * DMOD + ssg;
    const ushort* Bbase = xe + (size_t)(b * SRCN + n0 + sr) * DMOD + ssg;

    floatx4 acc[4][2];
    #pragma unroll
    for (int mi = 0; mi < 4; ++mi)
        #pragma unroll
        for (int ni = 0; ni < 2; ++ni)
            acc[mi][ni] = (floatx4){0.f, 0.f, 0.f, 0.f};

#define STAGE_SC(buf, kk) do { \
    _Pragma("unroll") \
    for (int i = 0; i < 4; ++i) { \
        const int cc = w * 4 + i; \
        gload_lds16(Abase + (size_t)(cc * 8) * DMOD + (kk), (void*)(As + (buf) * 8192 + cc * 512)); \
    } \
    _Pragma("unroll") \
    for (int i = 0; i < 2; ++i) { \
        const int cc = w * 2 + i; \
        gload_lds16(Bbase + (size_t)(cc * 8) * DMOD + (kk), (void*)(Bs + (buf) * 4096 + cc * 512)); \
    } } while (0)

    STAGE_SC(0, 0);
    __syncthreads();
    #pragma unroll
    for (int t = 0; t < 8; ++t) {
        const int cur = t & 1;
        if (t < 7) STAGE_SC(cur ^ 1, (t + 1) * 64);
        #pragma unroll
        for (int s2 = 0; s2 < 2; ++s2) {
            const int sg = s2 * 4 + q;
            short8 af[4], bf[2];
            #pragma unroll
            for (int mi = 0; mi < 4; ++mi)
                af[mi] = *(const short8*)(As + cur * 8192 + LSLOT(wm * 64 + mi * 16 + l15, sg));
            #pragma unroll
            for (int ni = 0; ni < 2; ++ni)
                bf[ni] = *(const short8*)(Bs + cur * 4096 + LSLOT(wn * 32 + ni * 16 + l15, sg));
            #pragma unroll
            for (int mi = 0; mi < 4; ++mi)
                #pragma unroll
                for (int ni = 0; ni < 2; ++ni)
                    acc[mi][ni] = __builtin_amdgcn_mfma_f32_16x16x32_bf16(
                        af[mi], bf[ni], acc[mi][ni], 0, 0, 0);
        }
        __syncthreads();
    }
#undef STAGE_SC

    #pragma unroll
    for (int ni = 0; ni < 2; ++ni) {
        const int col = n0 + wn * 32 + ni * 16 + l15;
        const float msk = (x[b * SRCN + col] == 0) ? -1e9f : 0.0f;
        #pragma unroll
        for (int mi = 0; mi < 4; ++mi) {
            const int row0 = wm * 64 + mi * 16 + q * 4;
            #pragma unroll
            for (int r = 0; r < 4; ++r)
                a_out[((size_t)b * SEQL + row0 + r) * SRCN + col] = acc[mi][ni][r] + msk;
        }
    }
}

// ---------------------------------------------------------------------------
// Row softmax over 1024 (mask already applied); fp32 in place + bf16 copy
// ---------------------------------------------------------------------------
__global__ __launch_bounds__(256) void k_softmax(
    float* __restrict__ a, ushort* __restrict__ abf)
{
    const int row = blockIdx.x;          // b*128+s
    float* p = a + (size_t)row * SRCN;
    ushort* pb = abf + (size_t)row * SRCN;
    const int tid = threadIdx.x;
    const int wave = tid >> 6, lane = tid & 63;

    float4 v = *(const float4*)(p + tid * 4);

    float mx = fmaxf(fmaxf(v.x, v.y), fmaxf(v.z, v.w));
    #pragma unroll
    for (int off = 32; off > 0; off >>= 1)
        mx = fmaxf(mx, __shfl_down(mx, off, 64));
    __shared__ float redm[4];
    if (lane == 0) redm[wave] = mx;
    __syncthreads();
    mx = fmaxf(fmaxf(redm[0], redm[1]), fmaxf(redm[2], redm[3]));

    const float e0 = __expf(v.x - mx);
    const float e1 = __expf(v.y - mx);
    const float e2 = __expf(v.z - mx);
    const float e3 = __expf(v.w - mx);

    float sm = e0 + e1 + e2 + e3;
    #pragma unroll
    for (int off = 32; off > 0; off >>= 1)
        sm += __shfl_down(sm, off, 64);
    __shared__ float reds[4];
    if (lane == 0) reds[wave] = sm;
    __syncthreads();
    sm = reds[0] + reds[1] + reds[2] + reds[3];

    const float inv = 1.0f / sm;
    float4 o;
    o.x = e0 * inv; o.y = e1 * inv; o.z = e2 * inv; o.w = e3 * inv;
    *(float4*)(p + tid * 4) = o;
    ushort4 ob;
    ob.x = f2b(o.x); ob.y = f2b(o.y); ob.z = f2b(o.z); ob.w = f2b(o.w);
    *(ushort4*)(pb + tid * 4) = ob;
}

// ---------------------------------------------------------------------------
// GEMM3 (2-phase pipelined): out[b][m0:m0+64][n0:n0+64] = abf_b @ xet_b^T
// (K=1024). Tile 64x64 dbuf BK=64, 16 steps, 512 blocks.
// ---------------------------------------------------------------------------
__global__ __launch_bounds__(256) void k_gemm_out(
    const ushort* __restrict__ abf, const ushort* __restrict__ xet,
    float* __restrict__ outp)
{
    __shared__ ushort As[2 * 4096];   // dbuf x (64 rows x 64 k)
    __shared__ ushort Bs[2 * 4096];
    const int f = blockIdx.x;            // 0..511
    const int g = f >> 3;
    const int b = ((g & 3) << 3) | (f & 7);
    const int h = g >> 2;                // 0..15
    const int m = h & 1, n = h >> 1;     // 2 m x 8 n
    const int tid = threadIdx.x;
    const int w = tid >> 6, lane = tid & 63;
    const int l15 = lane & 15, q = lane >> 4;
    const int wm = w >> 1, wn = w & 1;
    const int m0 = m * 64, n0 = n * 64;

    const int sr = lane >> 3;
    const int ssg = ((lane & 7) ^ sr) * 8;

    const ushort* Abase = abf + (size_t)(b * SEQL + m0 + sr) * SRCN + ssg;
    const ushort* Bbase = xet + (size_t)(b * DMOD + n0 + sr) * SRCN + ssg;

    floatx4 acc[2][2];
    #pragma unroll
    for (int mi = 0; mi < 2; ++mi)
        #pragma unroll
        for (int ni = 0; ni < 2; ++ni)
            acc[mi][ni] = (floatx4){0.f, 0.f, 0.f, 0.f};

#define STAGE_O(buf, kk) do { \
    _Pragma("unroll") \
    for (int i = 0; i < 2; ++i) { \
        const int cc = w * 2 + i; \
        gload_lds16(Abase + (size_t)(cc * 8) * SRCN + (kk), (void*)(As + (buf) * 4096 + cc * 512)); \
        gload_lds16(Bbase + (size_t)(cc * 8) * SRCN + (kk), (void*)(Bs + (buf) * 4096 + cc * 512)); \
    } } while (0)

    STAGE_O(0, 0);
    __syncthreads();
    #pragma unroll
    for (int t = 0; t < 16; ++t) {
        const int cur = t & 1;
        if (t < 15) STAGE_O(cur ^ 1, (t + 1) * 64);
        #pragma unroll
        for (int s2 = 0; s2 < 2; ++s2) {
            const int sg = s2 * 4 + q;
            short8 af[2], bf[2];
            #pragma unroll
            for (int mi = 0; mi < 2; ++mi)
                af[mi] = *(const short8*)(As + cur * 4096 + LSLOT(wm * 32 + mi * 16 + l15, sg));
            #pragma unroll
            for (int ni = 0; ni < 2; ++ni)
                bf[ni] = *(const short8*)(Bs + cur * 4096 + LSLOT(wn * 32 + ni * 16 + l15, sg));
            #pragma unroll
            for (int mi = 0; mi < 2; ++mi)
                #pragma unroll
                for (int ni = 0; ni < 2; ++ni)
                    acc[mi][ni] = __builtin_amdgcn_mfma_f32_16x16x32_bf16(
                        af[mi], bf[ni], acc[mi][ni], 0, 0, 0);
        }
        __syncthreads();
    }
#undef STAGE_O

    #pragma unroll
    for (int ni = 0; ni < 2; ++ni) {
        const int col = n0 + wn * 32 + ni * 16 + l15;
        #pragma unroll
        for (int mi = 0; mi < 2; ++mi) {
            const int row0 = m0 + wm * 32 + mi * 16 + q * 4;
            #pragma unroll
            for (int r = 0; r < 4; ++r)
                outp[((size_t)b * SEQL + row0 + r) * DMOD + col] = acc[mi][ni][r];
        }
    }
}

// ---------------------------------------------------------------------------
extern "C" void kernel_launch(void* const* d_in, const int* in_sizes, int n_in,
                              void* d_out, int out_size, void* d_ws, size_t ws_size,
                              hipStream_t stream)
{
    const int*   x    = (const int*)d_in[0];    // [32,1024]
    const int*   yc   = (const int*)d_in[1];    // [32,640]
    const float* Femb = (const float*)d_in[2];  // [32000,512]
    const float* Gemb = (const float*)d_in[3];  // [32000,512]
    const float* Pw   = (const float*)d_in[4];  // [2560,512]
    const float* Pb   = (const float*)d_in[5];  // [512]

    float* out_p = (float*)d_out;                         // [32,128,512]
    float* a_p   = out_p + (size_t)BATCH * SEQL * DMOD;   // [32,128,1024]

    // Workspace:
    //   yce  [0,         20971520)  live: gather .. gemm_py
    //   abf  [0,          8388608)  live: softmax .. gemm_out (aliases dead yce)
    //   pwt  [20971520,  23592960)  live: gather .. gemm_py
    //   xe   [23592960,  57147392)  live: gather .. gemm_sc
    //   xet  [57147392,  90701824)  live: gather .. gemm_out
    //   part [90701824, 107479040)  live: gemm_py .. red2  (2 x 8.39 MB fp32)
    //   py   [107479040,111673344)  live: red2 .. gemm_sc
    char* ws = (char*)d_ws;
    ushort* yce  = (ushort*)(ws);
    ushort* abf  = (ushort*)(ws);
    ushort* pwt  = (ushort*)(ws + 20971520);
    ushort* xe   = (ushort*)(ws + 23592960);
    ushort* xet  = (ushort*)(ws + 57147392);
    float*  part = (float*) (ws + 90701824);
    ushort* py   = (ushort*)(ws + 107479040);

    dim3 blk(256);
    // all gathers in one launch: 4096 yce + 320 pwt + 2048 xe/xet
    k_gather<<<dim3(6464), blk, 0, stream>>>(yc, Gemb, yce, Pw, pwt, x, Femb, xe, xet);

    // GEMM1 split-K=2, 128x64 tiles, 512 blocks + fused reduce/bias
    k_gemm_py<<<dim3(512), blk, 0, stream>>>(yce, pwt, part);
    k_red2<<<dim3(2048), blk, 0, stream>>>(part, Pb, py);

    // GEMM2 128x64 tiles: 512 blocks, mask fused
    k_gemm_sc<<<dim3(512), blk, 0, stream>>>(py, x, xe, a_p);
    k_softmax<<<dim3(4096), blk, 0, stream>>>(a_p, abf);
    // GEMM3 64x64 BK=64 dbuf: 512 blocks
    k_gemm_out<<<dim3(512), blk, 0, stream>>>(abf, xet, out_p);
}

// Round 6
// 216.940 us; speedup vs baseline: 1.0670x; 1.0670x over previous
//
#include <hip/hip_runtime.h>
#include <hip/hip_bf16.h>
#include <stdint.h>

#define BATCH 32
#define SRCN 1024
#define SEQL 128
#define CTXN 5
#define DMOD 512

typedef __attribute__((ext_vector_type(8))) short short8;
typedef __attribute__((ext_vector_type(4))) float floatx4;

typedef __attribute__((address_space(3))) void lds_t;
typedef __attribute__((address_space(1))) void glb_t;

__device__ __forceinline__ void gload_lds16(const void* g, void* l) {
    __builtin_amdgcn_global_load_lds((const glb_t*)g, (lds_t*)l, 16, 0, 0);
}

__device__ __forceinline__ ushort f2b(float f) {
    __hip_bfloat16 h = __float2bfloat16(f);
    return *reinterpret_cast<ushort*>(&h);
}

// Swizzled LDS slot for (tile-local row m, k-seg sg): slot = m*8 + (sg^(m&7)),
// slot = 8 ushorts (16B). Staging chunk cc (1KB = 8 rows x 64k): lane i stages
// row cc*8+(i>>3), k-seg (i&7)^(i>>3) -> 8 contiguous 128B runs, and the LDS
// dest is exactly chunkbase + lane*16 (wave-uniform base + lane*size).
#define LSLOT(m, sg) ((((m) << 3) | ((sg) ^ ((m) & 7))) << 3)

// ---------------------------------------------------------------------------
// Gather-YP: blocks [0,4096) yce gather; [4096,4416) P_w transpose.
// (Round-1 verbatim arms; 17.7KB LDS keeps 8 blocks/CU.)
// ---------------------------------------------------------------------------
__global__ __launch_bounds__(256) void k_gather_yp(
    const int* __restrict__ yc, const float* __restrict__ G,
    ushort* __restrict__ yce,
    const float* __restrict__ Pw, ushort* __restrict__ Pwt)
{
    __shared__ __align__(16) char smem[17408];
    const int tid = threadIdx.x;
    const int bid = blockIdx.x;
    if (bid < 4096) {
        // ---- gather yce[b][s][c*512 + d] bf16 ----
        const int r = bid;                   // b*128+s
        const int b = r >> 7, s = r & 127;
        for (int i = tid; i < 640; i += 256) {
            const int c = i >> 7;            // context slot 0..4
            const int tok = yc[b * (SEQL * CTXN) + s * CTXN + c];
            const float4 v = *(const float4*)(G + (size_t)tok * DMOD + (i & 127) * 4);
            ushort4 o;
            o.x = f2b(v.x); o.y = f2b(v.y); o.z = f2b(v.z); o.w = f2b(v.w);
            *(ushort4*)(yce + (size_t)r * 2560 + i * 4) = o;
        }
    } else {
        // ---- transpose P_w [2560][512] -> Pwt [512][2560] bf16 ----
        float* t = (float*)smem;             // [64][68]
        const int id = bid - 4096;           // 0..319
        const int k0 = (id % 40) * 64, n0 = (id / 40) * 64;
        #pragma unroll
        for (int it = 0; it < 4; ++it) {
            const int c = tid + it * 256;
            const int kr = c >> 4, c4 = c & 15;
            const float4 v = *(const float4*)(Pw + (size_t)(k0 + kr) * DMOD + n0 + c4 * 4);
            t[kr * 68 + c4 * 4 + 0] = v.x; t[kr * 68 + c4 * 4 + 1] = v.y;
            t[kr * 68 + c4 * 4 + 2] = v.z; t[kr * 68 + c4 * 4 + 3] = v.w;
        }
        __syncthreads();
        #pragma unroll
        for (int it = 0; it < 2; ++it) {
            const int c = tid + it * 256;
            const int n = c >> 3, seg = c & 7;
            ushort4 o0, o1;
            o0.x = f2b(t[(seg * 8 + 0) * 68 + n]); o0.y = f2b(t[(seg * 8 + 1) * 68 + n]);
            o0.z = f2b(t[(seg * 8 + 2) * 68 + n]); o0.w = f2b(t[(seg * 8 + 3) * 68 + n]);
            o1.x = f2b(t[(seg * 8 + 4) * 68 + n]); o1.y = f2b(t[(seg * 8 + 5) * 68 + n]);
            o1.z = f2b(t[(seg * 8 + 6) * 68 + n]); o1.w = f2b(t[(seg * 8 + 7) * 68 + n]);
            ushort* dst = Pwt + (size_t)(n0 + n) * 2560 + k0 + seg * 8;
            *(ushort4*)dst = o0; *(ushort4*)(dst + 4) = o1;
        }
    }
}

// ---------------------------------------------------------------------------
// Gather-X: F rows -> xe[b][x][d] AND xet[b][d][x], 64x-rows x 256-d tiles.
// Each wave reads 1KB contiguous runs of a token row (vs 256B granules at
// 64-d tiles); each F-row is fetched by 2 blocks instead of 8.
// LDS tile [64][256] ushorts, unit-swizzled u' = u ^ (row>>3) so the
// transpose read (8 x-contig elems, fixed d) is <=2-way bank aliased.
// ---------------------------------------------------------------------------
__global__ __launch_bounds__(256) void k_gather_x(
    const int* __restrict__ x, const float* __restrict__ F,
    ushort* __restrict__ xe, ushort* __restrict__ xet)
{
    __shared__ __align__(16) ushort t[64 * 256];  // 32KB
    __shared__ int toks[64];
    const int tid = threadIdx.x;
    const int id = blockIdx.x;           // 0..1023
    const int z = id >> 5;               // batch
    const int rem = id & 31;             // 16 x-tiles x 2 d-tiles
    const int x0 = (rem & 15) * 64, d0 = (rem >> 4) * 256;

    if (tid < 64) toks[tid] = x[z * SRCN + x0 + tid];
    __syncthreads();

    #pragma unroll
    for (int it = 0; it < 16; ++it) {
        const int c = tid + it * 256;    // 4096: 64 rows x 64 float4
        const int row = c >> 6, j = c & 63;
        const int tok = toks[row];
        const float4 v = *(const float4*)(F + (size_t)tok * DMOD + d0 + j * 4);
        ushort4 o;
        o.x = f2b(v.x); o.y = f2b(v.y); o.z = f2b(v.z); o.w = f2b(v.w);
        const int u = j ^ ((row >> 3) & 7);
        *(ushort4*)&t[row * 256 + u * 4] = o;
        *(ushort4*)(xe + (size_t)(z * SRCN + x0 + row) * DMOD + d0 + j * 4) = o;
    }
    __syncthreads();
    #pragma unroll
    for (int it = 0; it < 8; ++it) {
        const int c = tid + it * 256;    // 2048 outs: 8 xs (fast) x 256 d
        const int xs = c & 7, d = c >> 3;
        short8 o;
        #pragma unroll
        for (int r = 0; r < 8; ++r)
            o[r] = (short)t[(xs * 8 + r) * 256 + (((d >> 2) ^ xs) << 2) + (d & 3)];
        *(short8*)(xet + (size_t)(z * DMOD + d0 + d) * SRCN + x0 + xs * 8) = o;
    }
}

// ---------------------------------------------------------------------------
// GEMM1 (full-K, no split): py = yce @ pwt^T + Pb, bf16 out.  (Round-1.)
// Tile 64m x 64n, BK=128 (two 64-k sub-chunks per barrier), K=2560 (20 iters).
// 512 blocks (2/CU), chunked XCD swizzle so same-m blocks share an L2.
// ---------------------------------------------------------------------------
__global__ __launch_bounds__(256) void k_gemm_py(
    const ushort* __restrict__ yce, const ushort* __restrict__ pwt,
    const float* __restrict__ Pb, ushort* __restrict__ py)
{
    __shared__ ushort As[2 * 8 * 512];   // 2 sub-k x (64 rows x 64 k)
    __shared__ ushort Bs[2 * 8 * 512];
    const int f = blockIdx.x;            // 0..511
    const int wg = ((f & 7) << 6) | (f >> 3);   // chunked per-XCD
    const int m = wg >> 3, n = wg & 7;   // 64 m x 8 n
    const int tid = threadIdx.x;
    const int w = tid >> 6, lane = tid & 63;
    const int l15 = lane & 15, q = lane >> 4;
    const int wm = w >> 1, wn = w & 1;
    const int m0 = m * 64, n0 = n * 64;

    const int sr = lane >> 3;
    const int ssg = ((lane & 7) ^ sr) * 8;

    const ushort* Abase = yce + (size_t)(m0 + sr) * 2560 + ssg;
    const ushort* Bbase = pwt + (size_t)(n0 + sr) * 2560 + ssg;

    floatx4 acc[2][2];
    #pragma unroll
    for (int mi = 0; mi < 2; ++mi)
        #pragma unroll
        for (int ni = 0; ni < 2; ++ni)
            acc[mi][ni] = (floatx4){0.f, 0.f, 0.f, 0.f};

    for (int kk = 0; kk < 2560; kk += 128) {
        __syncthreads();
        #pragma unroll
        for (int sub = 0; sub < 2; ++sub) {
            #pragma unroll
            for (int i = 0; i < 2; ++i) {
                const int cc = w * 2 + i;
                gload_lds16(Abase + (size_t)(cc * 8) * 2560 + kk + sub * 64,
                            (void*)(As + sub * 4096 + cc * 512));
                gload_lds16(Bbase + (size_t)(cc * 8) * 2560 + kk + sub * 64,
                            (void*)(Bs + sub * 4096 + cc * 512));
            }
        }
        __syncthreads();
        #pragma unroll
        for (int sub = 0; sub < 2; ++sub) {
            #pragma unroll
            for (int s2 = 0; s2 < 2; ++s2) {
                const int sg = s2 * 4 + q;
                short8 af[2], bf[2];
                #pragma unroll
                for (int mi = 0; mi < 2; ++mi)
                    af[mi] = *(const short8*)(As + sub * 4096 + LSLOT(wm * 32 + mi * 16 + l15, sg));
                #pragma unroll
                for (int ni = 0; ni < 2; ++ni)
                    bf[ni] = *(const short8*)(Bs + sub * 4096 + LSLOT(wn * 32 + ni * 16 + l15, sg));
                #pragma unroll
                for (int mi = 0; mi < 2; ++mi)
                    #pragma unroll
                    for (int ni = 0; ni < 2; ++ni)
                        acc[mi][ni] = __builtin_amdgcn_mfma_f32_16x16x32_bf16(
                            af[mi], bf[ni], acc[mi][ni], 0, 0, 0);
            }
        }
    }

    #pragma unroll
    for (int ni = 0; ni < 2; ++ni) {
        const int col = n0 + wn * 32 + ni * 16 + l15;
        const float bias = Pb[col];
        #pragma unroll
        for (int mi = 0; mi < 2; ++mi) {
            const int row0 = m0 + wm * 32 + mi * 16 + q * 4;
            #pragma unroll
            for (int r = 0; r < 4; ++r)
                py[(size_t)(row0 + r) * DMOD + col] = f2b(acc[mi][ni][r] + bias);
        }
    }
}

// ---------------------------------------------------------------------------
// GEMM2: a[b][0:128][n0:n0+64] = py_b @ xe_b^T (K=512), mask fused, fp32 out.
// Tile 128m x 64n, 512 blocks, per-batch XCD swizzle (f&7 == b&7). (Round-1.)
// ---------------------------------------------------------------------------
__global__ __launch_bounds__(256) void k_gemm_sc(
    const ushort* __restrict__ py, const int* __restrict__ x,
    const ushort* __restrict__ xe, float* __restrict__ a_out)
{
    __shared__ ushort As[16 * 512];   // 128 rows x 64 k
    __shared__ ushort Bs[8 * 512];    // 64 rows x 64 k
    const int f = blockIdx.x;         // 0..511
    const int g = f >> 3;
    const int b = ((g & 3) << 3) | (f & 7);
    const int n = g >> 2;             // 0..15
    const int tid = threadIdx.x;
    const int w = tid >> 6, lane = tid & 63;
    const int l15 = lane & 15, q = lane >> 4;
    const int wm = w >> 1, wn = w & 1;
    const int n0 = n * 64;

    const int sr = lane >> 3;
    const int ssg = ((lane & 7) ^ sr) * 8;

    const ushort* Abase = py + (size_t)(b * SEQL + sr) * DMOD + ssg;
    const ushort* Bbase = xe + (size_t)(b * SRCN + n0 + sr) * DMOD + ssg;

    floatx4 acc[4][2];
    #pragma unroll
    for (int mi = 0; mi < 4; ++mi)
        #pragma unroll
        for (int ni = 0; ni < 2; ++ni)
            acc[mi][ni] = (floatx4){0.f, 0.f, 0.f, 0.f};

    for (int kk = 0; kk < DMOD; kk += 64) {
        __syncthreads();
        #pragma unroll
        for (int i = 0; i < 4; ++i) {
            const int cc = w * 4 + i;
            gload_lds16(Abase + (size_t)(cc * 8) * DMOD + kk, (void*)(As + cc * 512));
        }
        #pragma unroll
        for (int i = 0; i < 2; ++i) {
            const int cc = w * 2 + i;
            gload_lds16(Bbase + (size_t)(cc * 8) * DMOD + kk, (void*)(Bs + cc * 512));
        }
        __syncthreads();
        #pragma unroll
        for (int s2 = 0; s2 < 2; ++s2) {
            const int sg = s2 * 4 + q;
            short8 af[4], bf[2];
            #pragma unroll
            for (int mi = 0; mi < 4; ++mi)
                af[mi] = *(const short8*)(As + LSLOT(wm * 64 + mi * 16 + l15, sg));
            #pragma unroll
            for (int ni = 0; ni < 2; ++ni)
                bf[ni] = *(const short8*)(Bs + LSLOT(wn * 32 + ni * 16 + l15, sg));
            #pragma unroll
            for (int mi = 0; mi < 4; ++mi)
                #pragma unroll
                for (int ni = 0; ni < 2; ++ni)
                    acc[mi][ni] = __builtin_amdgcn_mfma_f32_16x16x32_bf16(
                        af[mi], bf[ni], acc[mi][ni], 0, 0, 0);
        }
    }

    #pragma unroll
    for (int ni = 0; ni < 2; ++ni) {
        const int col = n0 + wn * 32 + ni * 16 + l15;
        const float msk = (x[b * SRCN + col] == 0) ? -1e9f : 0.0f;
        #pragma unroll
        for (int mi = 0; mi < 4; ++mi) {
            const int row0 = wm * 64 + mi * 16 + q * 4;
            #pragma unroll
            for (int r = 0; r < 4; ++r)
                a_out[((size_t)b * SEQL + row0 + r) * SRCN + col] = acc[mi][ni][r] + msk;
        }
    }
}

// ---------------------------------------------------------------------------
// Row softmax over 1024 (mask already applied); fp32 in place + bf16 copy
// ---------------------------------------------------------------------------
__global__ __launch_bounds__(256) void k_softmax(
    float* __restrict__ a, ushort* __restrict__ abf)
{
    const int row = blockIdx.x;          // b*128+s
    float* p = a + (size_t)row * SRCN;
    ushort* pb = abf + (size_t)row * SRCN;
    const int tid = threadIdx.x;
    const int wave = tid >> 6, lane = tid & 63;

    float4 v = *(const float4*)(p + tid * 4);

    float mx = fmaxf(fmaxf(v.x, v.y), fmaxf(v.z, v.w));
    #pragma unroll
    for (int off = 32; off > 0; off >>= 1)
        mx = fmaxf(mx, __shfl_down(mx, off, 64));
    __shared__ float redm[4];
    if (lane == 0) redm[wave] = mx;
    __syncthreads();
    mx = fmaxf(fmaxf(redm[0], redm[1]), fmaxf(redm[2], redm[3]));

    const float e0 = __expf(v.x - mx);
    const float e1 = __expf(v.y - mx);
    const float e2 = __expf(v.z - mx);
    const float e3 = __expf(v.w - mx);

    float sm = e0 + e1 + e2 + e3;
    #pragma unroll
    for (int off = 32; off > 0; off >>= 1)
        sm += __shfl_down(sm, off, 64);
    __shared__ float reds[4];
    if (lane == 0) reds[wave] = sm;
    __syncthreads();
    sm = reds[0] + reds[1] + reds[2] + reds[3];

    const float inv = 1.0f / sm;
    float4 o;
    o.x = e0 * inv; o.y = e1 * inv; o.z = e2 * inv; o.w = e3 * inv;
    *(float4*)(p + tid * 4) = o;
    ushort4 ob;
    ob.x = f2b(o.x); ob.y = f2b(o.y); ob.z = f2b(o.z); ob.w = f2b(o.w);
    *(ushort4*)(pb + tid * 4) = ob;
}

// ---------------------------------------------------------------------------
// GEMM3: out[b][m0:m0+64][n0:n0+64] = abf_b @ xet_b^T (K=1024), fp32 out.
// Tile 64x64, BK=128 (two 64-k sub-chunks per barrier), 512 blocks. (Round-1.)
// ---------------------------------------------------------------------------
__global__ __launch_bounds__(256) void k_gemm_out(
    const ushort* __restrict__ abf, const ushort* __restrict__ xet,
    float* __restrict__ outp)
{
    __shared__ ushort As[2 * 8 * 512];   // 2 sub-k x (64 rows x 64 k)
    __shared__ ushort Bs[2 * 8 * 512];
    const int f = blockIdx.x;            // 0..511
    const int g = f >> 3;
    const int b = ((g & 3) << 3) | (f & 7);
    const int h = g >> 2;                // 0..15
    const int m = h & 1, n = h >> 1;     // 2 m x 8 n
    const int tid = threadIdx.x;
    const int w = tid >> 6, lane = tid & 63;
    const int l15 = lane & 15, q = lane >> 4;
    const int wm = w >> 1, wn = w & 1;
    const int m0 = m * 64, n0 = n * 64;

    const int sr = lane >> 3;
    const int ssg = ((lane & 7) ^ sr) * 8;

    const ushort* Abase = abf + (size_t)(b * SEQL + m0 + sr) * SRCN + ssg;
    const ushort* Bbase = xet + (size_t)(b * DMOD + n0 + sr) * SRCN + ssg;

    floatx4 acc[2][2];
    #pragma unroll
    for (int mi = 0; mi < 2; ++mi)
        #pragma unroll
        for (int ni = 0; ni < 2; ++ni)
            acc[mi][ni] = (floatx4){0.f, 0.f, 0.f, 0.f};

    for (int kk = 0; kk < SRCN; kk += 128) {
        __syncthreads();
        #pragma unroll
        for (int sub = 0; sub < 2; ++sub) {
            #pragma unroll
            for (int i = 0; i < 2; ++i) {
                const int cc = w * 2 + i;
                gload_lds16(Abase + (size_t)(cc * 8) * SRCN + kk + sub * 64,
                            (void*)(As + sub * 4096 + cc * 512));
                gload_lds16(Bbase + (size_t)(cc * 8) * SRCN + kk + sub * 64,
                            (void*)(Bs + sub * 4096 + cc * 512));
            }
        }
        __syncthreads();
        #pragma unroll
        for (int sub = 0; sub < 2; ++sub) {
            #pragma unroll
            for (int s2 = 0; s2 < 2; ++s2) {
                const int sg = s2 * 4 + q;
                short8 af[2], bf[2];
                #pragma unroll
                for (int mi = 0; mi < 2; ++mi)
                    af[mi] = *(const short8*)(As + sub * 4096 + LSLOT(wm * 32 + mi * 16 + l15, sg));
                #pragma unroll
                for (int ni = 0; ni < 2; ++ni)
                    bf[ni] = *(const short8*)(Bs + sub * 4096 + LSLOT(wn * 32 + ni * 16 + l15, sg));
                #pragma unroll
                for (int mi = 0; mi < 2; ++mi)
                    #pragma unroll
                    for (int ni = 0; ni < 2; ++ni)
                        acc[mi][ni] = __builtin_amdgcn_mfma_f32_16x16x32_bf16(
                            af[mi], bf[ni], acc[mi][ni], 0, 0, 0);
            }
        }
    }

    #pragma unroll
    for (int ni = 0; ni < 2; ++ni) {
        const int col = n0 + wn * 32 + ni * 16 + l15;
        #pragma unroll
        for (int mi = 0; mi < 2; ++mi) {
            const int row0 = m0 + wm * 32 + mi * 16 + q * 4;
            #pragma unroll
            for (int r = 0; r < 4; ++r)
                outp[((size_t)b * SEQL + row0 + r) * DMOD + col] = acc[mi][ni][r];
        }
    }
}

// ---------------------------------------------------------------------------
extern "C" void kernel_launch(void* const* d_in, const int* in_sizes, int n_in,
                              void* d_out, int out_size, void* d_ws, size_t ws_size,
                              hipStream_t stream)
{
    const int*   x    = (const int*)d_in[0];    // [32,1024]
    const int*   yc   = (const int*)d_in[1];    // [32,640]
    const float* Femb = (const float*)d_in[2];  // [32000,512]
    const float* Gemb = (const float*)d_in[3];  // [32000,512]
    const float* Pw   = (const float*)d_in[4];  // [2560,512]
    const float* Pb   = (const float*)d_in[5];  // [512]

    float* out_p = (float*)d_out;                         // [32,128,512]
    float* a_p   = out_p + (size_t)BATCH * SEQL * DMOD;   // [32,128,1024]

    // Workspace (round-1 layout):
    //   yce  [0,        20971520)  live: gather_yp .. gemm_py
    //   abf  [0,         8388608)  live: softmax .. gemm_out (aliases dead yce)
    //   pwt  [20971520, 23592960)  live: gather_yp .. gemm_py
    //   xe   [23592960, 57147392)  live: gather_x .. gemm_sc
    //   xet  [57147392, 90701824)  live: gather_x .. gemm_out
    //   py   [90701824, 94896128)  live: gemm_py .. gemm_sc
    char* ws = (char*)d_ws;
    ushort* yce  = (ushort*)(ws);
    ushort* abf  = (ushort*)(ws);
    ushort* pwt  = (ushort*)(ws + 20971520);
    ushort* xe   = (ushort*)(ws + 23592960);
    ushort* xet  = (ushort*)(ws + 57147392);
    ushort* py   = (ushort*)(ws + 90701824);

    dim3 blk(256);
    // yce + pwt gather (feeds GEMM1)
    k_gather_yp<<<dim3(4416), blk, 0, stream>>>(yc, Gemb, yce, Pw, pwt);
    // F gather with 64x256 tiles: full-row coalesced reads
    k_gather_x<<<dim3(1024), blk, 0, stream>>>(x, Femb, xe, xet);

    // GEMM1 full-K (no split, no reduce pass), bias fused, bf16 out
    k_gemm_py<<<dim3(512), blk, 0, stream>>>(yce, pwt, Pb, py);

    // GEMM2 128x64 tiles: 512 blocks, mask fused
    k_gemm_sc<<<dim3(512), blk, 0, stream>>>(py, x, xe, a_p);
    k_softmax<<<dim3(4096), blk, 0, stream>>>(a_p, abf);
    // GEMM3 64x64 BK=128: 512 blocks
    k_gemm_out<<<dim3(512), blk, 0, stream>>>(abf, xet, out_p);
}

// Round 7
// 215.591 us; speedup vs baseline: 1.0736x; 1.0063x over previous
//
#include <hip/hip_runtime.h>
#include <hip/hip_bf16.h>
#include <stdint.h>

#define BATCH 32
#define SRCN 1024
#define SEQL 128
#define CTXN 5
#define DMOD 512

typedef __attribute__((ext_vector_type(8))) short short8;
typedef __attribute__((ext_vector_type(4))) float floatx4;

typedef __attribute__((address_space(3))) void lds_t;
typedef __attribute__((address_space(1))) void glb_t;

__device__ __forceinline__ void gload_lds16(const void* g, void* l) {
    __builtin_amdgcn_global_load_lds((const glb_t*)g, (lds_t*)l, 16, 0, 0);
}

__device__ __forceinline__ ushort f2b(float f) {
    __hip_bfloat16 h = __float2bfloat16(f);
    return *reinterpret_cast<ushort*>(&h);
}

// Swizzled LDS slot for (tile-local row m, k-seg sg): slot = m*8 + (sg^(m&7)),
// slot = 8 ushorts (16B).
#define LSLOT(m, sg) ((((m) << 3) | ((sg) ^ ((m) & 7))) << 3)

// ---------------------------------------------------------------------------
// Merged gather (round-1 structure): blocks [0,4096) yce; [4096,4416) P_w
// transpose; [4416,6464) F gather -> xe + xet with 64x-rows x 128-d tiles:
// each token row fetched by 4 blocks in 512B runs (r1: 8 blocks x 256B).
// ---------------------------------------------------------------------------
__global__ __launch_bounds__(256) void k_gather(
    const int* __restrict__ yc, const float* __restrict__ G,
    ushort* __restrict__ yce,
    const float* __restrict__ Pw, ushort* __restrict__ Pwt,
    const int* __restrict__ x, const float* __restrict__ F,
    ushort* __restrict__ xe, ushort* __restrict__ xet)
{
    __shared__ __align__(16) char smem[17408];
    const int tid = threadIdx.x;
    const int bid = blockIdx.x;
    if (bid < 4096) {
        // ---- gather yce[b][s][c*512 + d] bf16 (r1 verbatim) ----
        const int r = bid;                   // b*128+s
        const int b = r >> 7, s = r & 127;
        for (int i = tid; i < 640; i += 256) {
            const int c = i >> 7;            // context slot 0..4
            const int tok = yc[b * (SEQL * CTXN) + s * CTXN + c];
            const float4 v = *(const float4*)(G + (size_t)tok * DMOD + (i & 127) * 4);
            ushort4 o;
            o.x = f2b(v.x); o.y = f2b(v.y); o.z = f2b(v.z); o.w = f2b(v.w);
            *(ushort4*)(yce + (size_t)r * 2560 + i * 4) = o;
        }
    } else if (bid < 4416) {
        // ---- transpose P_w [2560][512] -> Pwt [512][2560] bf16 (r1) ----
        float* t = (float*)smem;             // [64][68]
        const int id = bid - 4096;           // 0..319
        const int k0 = (id % 40) * 64, n0 = (id / 40) * 64;
        #pragma unroll
        for (int it = 0; it < 4; ++it) {
            const int c = tid + it * 256;
            const int kr = c >> 4, c4 = c & 15;
            const float4 v = *(const float4*)(Pw + (size_t)(k0 + kr) * DMOD + n0 + c4 * 4);
            t[kr * 68 + c4 * 4 + 0] = v.x; t[kr * 68 + c4 * 4 + 1] = v.y;
            t[kr * 68 + c4 * 4 + 2] = v.z; t[kr * 68 + c4 * 4 + 3] = v.w;
        }
        __syncthreads();
        #pragma unroll
        for (int it = 0; it < 2; ++it) {
            const int c = tid + it * 256;
            const int n = c >> 3, seg = c & 7;
            ushort4 o0, o1;
            o0.x = f2b(t[(seg * 8 + 0) * 68 + n]); o0.y = f2b(t[(seg * 8 + 1) * 68 + n]);
            o0.z = f2b(t[(seg * 8 + 2) * 68 + n]); o0.w = f2b(t[(seg * 8 + 3) * 68 + n]);
            o1.x = f2b(t[(seg * 8 + 4) * 68 + n]); o1.y = f2b(t[(seg * 8 + 5) * 68 + n]);
            o1.z = f2b(t[(seg * 8 + 6) * 68 + n]); o1.w = f2b(t[(seg * 8 + 7) * 68 + n]);
            ushort* dst = Pwt + (size_t)(n0 + n) * 2560 + k0 + seg * 8;
            *(ushort4*)dst = o0; *(ushort4*)(dst + 4) = o1;
        }
    } else {
        // ---- gather F rows -> xe[b][x][d] AND xet[b][d][x] bf16 ----
        // Tile 64 x-rows x 128 d. LDS [64][128] ushorts, group-swizzled
        // j' = j ^ (row>>3) (3-bit XOR, bijective; verified scheme from r6).
        ushort* t = (ushort*)smem;           // 16KB
        int* toks = (int*)(smem + 16384);    // 64 ints
        const int id = bid - 4416;           // 0..2047
        const int z = id >> 6;               // batch
        const int rem = id & 63;             // 16 x-tiles x 4 d-tiles
        const int x0 = (rem & 15) * 64, d0 = (rem >> 4) * 128;
        if (tid < 64) toks[tid] = x[z * SRCN + x0 + tid];
        __syncthreads();
        #pragma unroll
        for (int it = 0; it < 8; ++it) {
            const int c = tid + it * 256;    // 2048: 64 rows x 32 float4
            const int row = c >> 5, j = c & 31;
            const int tok = toks[row];
            const float4 v = *(const float4*)(F + (size_t)tok * DMOD + d0 + j * 4);
            ushort4 o;
            o.x = f2b(v.x); o.y = f2b(v.y); o.z = f2b(v.z); o.w = f2b(v.w);
            const int u = (j ^ ((row >> 3) & 7)) << 2;
            *(ushort4*)&t[row * 128 + u] = o;
            *(ushort4*)(xe + (size_t)(z * SRCN + x0 + row) * DMOD + d0 + j * 4) = o;
        }
        __syncthreads();
        #pragma unroll
        for (int it = 0; it < 4; ++it) {
            const int c = tid + it * 256;    // 1024 outs: 8 xs (fast) x 128 d
            const int xs = c & 7, d = c >> 3;
            short8 o;
            #pragma unroll
            for (int r = 0; r < 8; ++r)
                o[r] = (short)t[(xs * 8 + r) * 128 + (((d >> 2) ^ xs) << 2) + (d & 3)];
            *(short8*)(xet + (size_t)(z * DMOD + d0 + d) * SRCN + x0 + xs * 8) = o;
        }
    }
}

// ---------------------------------------------------------------------------
// GEMM1 (full-K, no split): py = yce @ pwt^T + Pb, bf16 out.  (Round-1.)
// Tile 64m x 64n, BK=128 (two 64-k sub-chunks per barrier), K=2560 (20 iters).
// 512 blocks (2/CU), chunked XCD swizzle so same-m blocks share an L2.
// ---------------------------------------------------------------------------
__global__ __launch_bounds__(256) void k_gemm_py(
    const ushort* __restrict__ yce, const ushort* __restrict__ pwt,
    const float* __restrict__ Pb, ushort* __restrict__ py)
{
    __shared__ ushort As[2 * 8 * 512];   // 2 sub-k x (64 rows x 64 k)
    __shared__ ushort Bs[2 * 8 * 512];
    const int f = blockIdx.x;            // 0..511
    const int wg = ((f & 7) << 6) | (f >> 3);   // chunked per-XCD
    const int m = wg >> 3, n = wg & 7;   // 64 m x 8 n
    const int tid = threadIdx.x;
    const int w = tid >> 6, lane = tid & 63;
    const int l15 = lane & 15, q = lane >> 4;
    const int wm = w >> 1, wn = w & 1;
    const int m0 = m * 64, n0 = n * 64;

    const int sr = lane >> 3;
    const int ssg = ((lane & 7) ^ sr) * 8;

    const ushort* Abase = yce + (size_t)(m0 + sr) * 2560 + ssg;
    const ushort* Bbase = pwt + (size_t)(n0 + sr) * 2560 + ssg;

    floatx4 acc[2][2];
    #pragma unroll
    for (int mi = 0; mi < 2; ++mi)
        #pragma unroll
        for (int ni = 0; ni < 2; ++ni)
            acc[mi][ni] = (floatx4){0.f, 0.f, 0.f, 0.f};

    for (int kk = 0; kk < 2560; kk += 128) {
        __syncthreads();
        #pragma unroll
        for (int sub = 0; sub < 2; ++sub) {
            #pragma unroll
            for (int i = 0; i < 2; ++i) {
                const int cc = w * 2 + i;
                gload_lds16(Abase + (size_t)(cc * 8) * 2560 + kk + sub * 64,
                            (void*)(As + sub * 4096 + cc * 512));
                gload_lds16(Bbase + (size_t)(cc * 8) * 2560 + kk + sub * 64,
                            (void*)(Bs + sub * 4096 + cc * 512));
            }
        }
        __syncthreads();
        #pragma unroll
        for (int sub = 0; sub < 2; ++sub) {
            #pragma unroll
            for (int s2 = 0; s2 < 2; ++s2) {
                const int sg = s2 * 4 + q;
                short8 af[2], bf[2];
                #pragma unroll
                for (int mi = 0; mi < 2; ++mi)
                    af[mi] = *(const short8*)(As + sub * 4096 + LSLOT(wm * 32 + mi * 16 + l15, sg));
                #pragma unroll
                for (int ni = 0; ni < 2; ++ni)
                    bf[ni] = *(const short8*)(Bs + sub * 4096 + LSLOT(wn * 32 + ni * 16 + l15, sg));
                #pragma unroll
                for (int mi = 0; mi < 2; ++mi)
                    #pragma unroll
                    for (int ni = 0; ni < 2; ++ni)
                        acc[mi][ni] = __builtin_amdgcn_mfma_f32_16x16x32_bf16(
                            af[mi], bf[ni], acc[mi][ni], 0, 0, 0);
            }
        }
    }

    #pragma unroll
    for (int ni = 0; ni < 2; ++ni) {
        const int col = n0 + wn * 32 + ni * 16 + l15;
        const float bias = Pb[col];
        #pragma unroll
        for (int mi = 0; mi < 2; ++mi) {
            const int row0 = m0 + wm * 32 + mi * 16 + q * 4;
            #pragma unroll
            for (int r = 0; r < 4; ++r)
                py[(size_t)(row0 + r) * DMOD + col] = f2b(acc[mi][ni][r] + bias);
        }
    }
}

// ---------------------------------------------------------------------------
// GEMM2: a[b][0:128][n0:n0+64] = py_b @ xe_b^T (K=512), mask fused, fp32 out.
// Tile 128m x 64n, 512 blocks, per-batch XCD swizzle (f&7 == b&7). (Round-1.)
// ---------------------------------------------------------------------------
__global__ __launch_bounds__(256) void k_gemm_sc(
    const ushort* __restrict__ py, const int* __restrict__ x,
    const ushort* __restrict__ xe, float* __restrict__ a_out)
{
    __shared__ ushort As[16 * 512];   // 128 rows x 64 k
    __shared__ ushort Bs[8 * 512];    // 64 rows x 64 k
    const int f = blockIdx.x;         // 0..511
    const int g = f >> 3;
    const int b = ((g & 3) << 3) | (f & 7);
    const int n = g >> 2;             // 0..15
    const int tid = threadIdx.x;
    const int w = tid >> 6, lane = tid & 63;
    const int l15 = lane & 15, q = lane >> 4;
    const int wm = w >> 1, wn = w & 1;
    const int n0 = n * 64;

    const int sr = lane >> 3;
    const int ssg = ((lane & 7) ^ sr) * 8;

    const ushort* Abase = py + (size_t)(b * SEQL + sr) * DMOD + ssg;
    const ushort* Bbase = xe + (size_t)(b * SRCN + n0 + sr) * DMOD + ssg;

    floatx4 acc[4][2];
    #pragma unroll
    for (int mi = 0; mi < 4; ++mi)
        #pragma unroll
        for (int ni = 0; ni < 2; ++ni)
            acc[mi][ni] = (floatx4){0.f, 0.f, 0.f, 0.f};

    for (int kk = 0; kk < DMOD; kk += 64) {
        __syncthreads();
        #pragma unroll
        for (int i = 0; i < 4; ++i) {
            const int cc = w * 4 + i;
            gload_lds16(Abase + (size_t)(cc * 8) * DMOD + kk, (void*)(As + cc * 512));
        }
        #pragma unroll
        for (int i = 0; i < 2; ++i) {
            const int cc = w * 2 + i;
            gload_lds16(Bbase + (size_t)(cc * 8) * DMOD + kk, (void*)(Bs + cc * 512));
        }
        __syncthreads();
        #pragma unroll
        for (int s2 = 0; s2 < 2; ++s2) {
            const int sg = s2 * 4 + q;
            short8 af[4], bf[2];
            #pragma unroll
            for (int mi = 0; mi < 4; ++mi)
                af[mi] = *(const short8*)(As + LSLOT(wm * 64 + mi * 16 + l15, sg));
            #pragma unroll
            for (int ni = 0; ni < 2; ++ni)
                bf[ni] = *(const short8*)(Bs + LSLOT(wn * 32 + ni * 16 + l15, sg));
            #pragma unroll
            for (int mi = 0; mi < 4; ++mi)
                #pragma unroll
                for (int ni = 0; ni < 2; ++ni)
                    acc[mi][ni] = __builtin_amdgcn_mfma_f32_16x16x32_bf16(
                        af[mi], bf[ni], acc[mi][ni], 0, 0, 0);
        }
    }

    #pragma unroll
    for (int ni = 0; ni < 2; ++ni) {
        const int col = n0 + wn * 32 + ni * 16 + l15;
        const float msk = (x[b * SRCN + col] == 0) ? -1e9f : 0.0f;
        #pragma unroll
        for (int mi = 0; mi < 4; ++mi) {
            const int row0 = wm * 64 + mi * 16 + q * 4;
            #pragma unroll
            for (int r = 0; r < 4; ++r)
                a_out[((size_t)b * SEQL + row0 + r) * SRCN + col] = acc[mi][ni][r] + msk;
        }
    }
}

// ---------------------------------------------------------------------------
// Row softmax over 1024 (mask already applied); fp32 in place + bf16 copy
// ---------------------------------------------------------------------------
__global__ __launch_bounds__(256) void k_softmax(
    float* __restrict__ a, ushort* __restrict__ abf)
{
    const int row = blockIdx.x;          // b*128+s
    float* p = a + (size_t)row * SRCN;
    ushort* pb = abf + (size_t)row * SRCN;
    const int tid = threadIdx.x;
    const int wave = tid >> 6, lane = tid & 63;

    float4 v = *(const float4*)(p + tid * 4);

    float mx = fmaxf(fmaxf(v.x, v.y), fmaxf(v.z, v.w));
    #pragma unroll
    for (int off = 32; off > 0; off >>= 1)
        mx = fmaxf(mx, __shfl_down(mx, off, 64));
    __shared__ float redm[4];
    if (lane == 0) redm[wave] = mx;
    __syncthreads();
    mx = fmaxf(fmaxf(redm[0], redm[1]), fmaxf(redm[2], redm[3]));

    const float e0 = __expf(v.x - mx);
    const float e1 = __expf(v.y - mx);
    const float e2 = __expf(v.z - mx);
    const float e3 = __expf(v.w - mx);

    float sm = e0 + e1 + e2 + e3;
    #pragma unroll
    for (int off = 32; off > 0; off >>= 1)
        sm += __shfl_down(sm, off, 64);
    __shared__ float reds[4];
    if (lane == 0) reds[wave] = sm;
    __syncthreads();
    sm = reds[0] + reds[1] + reds[2] + reds[3];

    const float inv = 1.0f / sm;
    float4 o;
    o.x = e0 * inv; o.y = e1 * inv; o.z = e2 * inv; o.w = e3 * inv;
    *(float4*)(p + tid * 4) = o;
    ushort4 ob;
    ob.x = f2b(o.x); ob.y = f2b(o.y); ob.z = f2b(o.z); ob.w = f2b(o.w);
    *(ushort4*)(pb + tid * 4) = ob;
}

// ---------------------------------------------------------------------------
// GEMM3: out[b][m0:m0+64][n0:n0+64] = abf_b @ xet_b^T (K=1024), fp32 out.
// Tile 64x64, BK=128 (two 64-k sub-chunks per barrier), 512 blocks. (Round-1.)
// ---------------------------------------------------------------------------
__global__ __launch_bounds__(256) void k_gemm_out(
    const ushort* __restrict__ abf, const ushort* __restrict__ xet,
    float* __restrict__ outp)
{
    __shared__ ushort As[2 * 8 * 512];   // 2 sub-k x (64 rows x 64 k)
    __shared__ ushort Bs[2 * 8 * 512];
    const int f = blockIdx.x;            // 0..511
    const int g = f >> 3;
    const int b = ((g & 3) << 3) | (f & 7);
    const int h = g >> 2;                // 0..15
    const int m = h & 1, n = h >> 1;     // 2 m x 8 n
    const int tid = threadIdx.x;
    const int w = tid >> 6, lane = tid & 63;
    const int l15 = lane & 15, q = lane >> 4;
    const int wm = w >> 1, wn = w & 1;
    const int m0 = m * 64, n0 = n * 64;

    const int sr = lane >> 3;
    const int ssg = ((lane & 7) ^ sr) * 8;

    const ushort* Abase = abf + (size_t)(b * SEQL + m0 + sr) * SRCN + ssg;
    const ushort* Bbase = xet + (size_t)(b * DMOD + n0 + sr) * SRCN + ssg;

    floatx4 acc[2][2];
    #pragma unroll
    for (int mi = 0; mi < 2; ++mi)
        #pragma unroll
        for (int ni = 0; ni < 2; ++ni)
            acc[mi][ni] = (floatx4){0.f, 0.f, 0.f, 0.f};

    for (int kk = 0; kk < SRCN; kk += 128) {
        __syncthreads();
        #pragma unroll
        for (int sub = 0; sub < 2; ++sub) {
            #pragma unroll
            for (int i = 0; i < 2; ++i) {
                const int cc = w * 2 + i;
                gload_lds16(Abase + (size_t)(cc * 8) * SRCN + kk + sub * 64,
                            (void*)(As + sub * 4096 + cc * 512));
                gload_lds16(Bbase + (size_t)(cc * 8) * SRCN + kk + sub * 64,
                            (void*)(Bs + sub * 4096 + cc * 512));
            }
        }
        __syncthreads();
        #pragma unroll
        for (int sub = 0; sub < 2; ++sub) {
            #pragma unroll
            for (int s2 = 0; s2 < 2; ++s2) {
                const int sg = s2 * 4 + q;
                short8 af[2], bf[2];
                #pragma unroll
                for (int mi = 0; mi < 2; ++mi)
                    af[mi] = *(const short8*)(As + sub * 4096 + LSLOT(wm * 32 + mi * 16 + l15, sg));
                #pragma unroll
                for (int ni = 0; ni < 2; ++ni)
                    bf[ni] = *(const short8*)(Bs + sub * 4096 + LSLOT(wn * 32 + ni * 16 + l15, sg));
                #pragma unroll
                for (int mi = 0; mi < 2; ++mi)
                    #pragma unroll
                    for (int ni = 0; ni < 2; ++ni)
                        acc[mi][ni] = __builtin_amdgcn_mfma_f32_16x16x32_bf16(
                            af[mi], bf[ni], acc[mi][ni], 0, 0, 0);
            }
        }
    }

    #pragma unroll
    for (int ni = 0; ni < 2; ++ni) {
        const int col = n0 + wn * 32 + ni * 16 + l15;
        #pragma unroll
        for (int mi = 0; mi < 2; ++mi) {
            const int row0 = m0 + wm * 32 + mi * 16 + q * 4;
            #pragma unroll
            for (int r = 0; r < 4; ++r)
                outp[((size_t)b * SEQL + row0 + r) * DMOD + col] = acc[mi][ni][r];
        }
    }
}

// ---------------------------------------------------------------------------
extern "C" void kernel_launch(void* const* d_in, const int* in_sizes, int n_in,
                              void* d_out, int out_size, void* d_ws, size_t ws_size,
                              hipStream_t stream)
{
    const int*   x    = (const int*)d_in[0];    // [32,1024]
    const int*   yc   = (const int*)d_in[1];    // [32,640]
    const float* Femb = (const float*)d_in[2];  // [32000,512]
    const float* Gemb = (const float*)d_in[3];  // [32000,512]
    const float* Pw   = (const float*)d_in[4];  // [2560,512]
    const float* Pb   = (const float*)d_in[5];  // [512]

    float* out_p = (float*)d_out;                         // [32,128,512]
    float* a_p   = out_p + (size_t)BATCH * SEQL * DMOD;   // [32,128,1024]

    // Workspace (round-1 layout):
    //   yce  [0,        20971520)  live: gather .. gemm_py
    //   abf  [0,         8388608)  live: softmax .. gemm_out (aliases dead yce)
    //   pwt  [20971520, 23592960)  live: gather .. gemm_py
    //   xe   [23592960, 57147392)  live: gather .. gemm_sc
    //   xet  [57147392, 90701824)  live: gather .. gemm_out
    //   py   [90701824, 94896128)  live: gemm_py .. gemm_sc
    char* ws = (char*)d_ws;
    ushort* yce  = (ushort*)(ws);
    ushort* abf  = (ushort*)(ws);
    ushort* pwt  = (ushort*)(ws + 20971520);
    ushort* xe   = (ushort*)(ws + 23592960);
    ushort* xet  = (ushort*)(ws + 57147392);
    ushort* py   = (ushort*)(ws + 90701824);

    dim3 blk(256);
    // merged gather: 4096 yce + 320 pwt + 2048 xe/xet (64x128 tiles)
    k_gather<<<dim3(6464), blk, 0, stream>>>(yc, Gemb, yce, Pw, pwt, x, Femb, xe, xet);

    // GEMM1 full-K, bias fused, bf16 out
    k_gemm_py<<<dim3(512), blk, 0, stream>>>(yce, pwt, Pb, py);

    // GEMM2 128x64 tiles: 512 blocks, mask fused
    k_gemm_sc<<<dim3(512), blk, 0, stream>>>(py, x, xe, a_p);
    k_softmax<<<dim3(4096), blk, 0, stream>>>(a_p, abf);
    // GEMM3 64x64 BK=128: 512 blocks
    k_gemm_out<<<dim3(512), blk, 0, stream>>>(abf, xet, out_p);
}